// Round 13
// baseline (240.604 us; speedup 1.0000x reference)
//
#include <hip/hip_runtime.h>

typedef unsigned short ushort_t;
typedef __attribute__((ext_vector_type(8))) short short8;
typedef __attribute__((ext_vector_type(8))) unsigned short u16x8;
typedef __attribute__((ext_vector_type(4))) float float4v;

#define MAXDEG 48

__device__ inline float b2f(ushort_t u) {
    unsigned x = ((unsigned)u) << 16;
    return __builtin_bit_cast(float, x);
}
__device__ inline ushort_t f2b(float f) {
    unsigned x = __builtin_bit_cast(unsigned, f);
    unsigned r = (x + 0x7fffu + ((x >> 16) & 1u)) >> 16;
    return (ushort_t)r;
}

// Wave-uniform int64-vs-int32 edge_index detection: load the int2 pair at
// edge slot e (valid bytes in BOTH layouts); int64-little-endian => odd word
// is always 0. Any nonzero odd word in the wave => int32.
__device__ inline void load_edge(const int* __restrict__ ei, int e, int E,
                                 int& s, int& d) {
    int ec = min(e, E - 1);
    int2 c64 = ((const int2*)ei)[ec];
    unsigned long long m = __ballot(c64.y != 0);
    if (m != 0ull) {  // int32 layout
        s = ei[ec];
        d = ei[(size_t)E + ec];
    } else {          // int64 layout
        s = c64.x;
        d = ((const int2*)ei)[(size_t)E + ec].x;
    }
}

// ---------------- mega kernel: count + direct slot scatter + casts ----------------
// packed[d] (u32): bits[31:22] = edge count, bits[21:0] = sum(w) in 6.16
// fixed point. The atomic's returned count IS the slot rank:
// edata[d*MAXDEG + r] = (src<<15)|wq15 written immediately.
// Edge blocks (stalled on the far-atomic wall, ~2% VALU; scope-null R1,
// padding-null R4 => fabric per-op limit ~8 ops/cycle chip-wide) are
// INTERLEAVED 1:2 with x-cast blocks (BW-bound): cast traffic hides under
// the atomic wall (A/B'd: present -> 46-50 us; removed -> 51-53 us, R8).

__global__ __launch_bounds__(256) void k_mega(const int* __restrict__ ei,
                                              const float* __restrict__ w,
                                              const float* __restrict__ x,
                                              const float* __restrict__ W1,
                                              const float* __restrict__ W2,
                                              unsigned* packed,
                                              unsigned* __restrict__ edata,
                                              ushort_t* __restrict__ xb_raw,
                                              ushort_t* __restrict__ W1b,
                                              ushort_t* __restrict__ W2b,
                                              int E, int Nn, int gE, int gX) {
    int b = blockIdx.x;
    bool isEdge;
    int widx;
    if (3 * gE <= (int)gridDim.x) {  // interleaved layout: edge at b%3==0
        if (b < 3 * gE) {
            if (b % 3 == 0) { isEdge = true;  widx = b / 3; }
            else            { isEdge = false; widx = b - b / 3 - 1; }
        } else {
            isEdge = false; widx = b - gE;
        }
    } else {  // fallback: contiguous sections
        isEdge = b < gE;
        widx = isEdge ? b : b - gE;
    }

    if (isEdge) {
        int e = widx * 256 + threadIdx.x;
        int s, d;
        load_edge(ei, e, E, s, d);
        if (e < E) {
            if ((unsigned)s < (unsigned)Nn && (unsigned)d < (unsigned)Nn) {
                float wv = w[e];
                unsigned fx = (unsigned)(wv * 65536.0f + 0.5f);
                unsigned old = atomicAdd(packed + d, (1u << 22) | fx);
                int r = (int)(old >> 22);
                if (r < MAXDEG) {
                    unsigned wq = (unsigned)(wv * 32768.0f + 0.5f);
                    wq = min(wq, 32767u);
                    edata[(size_t)d * MAXDEG + r] = ((unsigned)s << 15) | wq;
                }
            }
        }
    } else if (widx < gX) {
        int i = widx * 256 + threadIdx.x;  // float4 index
        if (i < Nn * 32) {
            float4v v = ((const float4v*)x)[i];
            ushort4 o;
            o.x = f2b(v[0]); o.y = f2b(v[1]); o.z = f2b(v[2]); o.w = f2b(v[3]);
            ((ushort4*)xb_raw)[i] = o;
        }
    } else {
        int i = (widx - gX) * 256 + threadIdx.x;
        if (i < 32768) W1b[i] = f2b(W1[i]);
        else if (i < 65536) W2b[i - 32768] = f2b(W2[i - 32768]);
    }
}

// ---------------- xscale: xb = bf16(dinv[v] * xb_raw[v]) + dinv table ----------------
// Folding dinv[src] into the STORED rows removes the per-edge dinv gather
// from both agg kernels (R8: -22 us combined). Reads bf16 xb_raw (12.8 MB).

__global__ __launch_bounds__(256) void k_xscale(const ushort_t* __restrict__ xb_raw,
                                                const unsigned* __restrict__ packed,
                                                float* __restrict__ dinv,
                                                ushort_t* __restrict__ xb, int Nn) {
    int v = (blockIdx.x * blockDim.x + threadIdx.x) >> 5;
    int hl = threadIdx.x & 31;
    if (v >= Nn) return;
    unsigned pk = packed[v];
    float dv = rsqrtf(1.0f + (float)(pk & 0x3FFFFFu) * (1.0f / 65536.0f));
    if (hl == 0) dinv[v] = dv;
    ushort4 xr = ((const ushort4*)(xb_raw + (size_t)v * 128))[hl];
    ushort4 o;
    o.x = f2b(b2f(xr.x) * dv); o.y = f2b(b2f(xr.y) * dv);
    o.z = f2b(b2f(xr.z) * dv); o.w = f2b(b2f(xr.w) * dv);
    ((ushort4*)(xb + (size_t)v * 128))[hl] = o;
}

// ---------------- aggregation 1: L2-RESIDENT 4-PASS CHUNKED gather ----------------
// Hypothesis test (R13): aggs are L3-random-BW bound -- the gather stream
// (800K x 256 B = 205 MB) random-accesses a 12.8 MB table, only ~31% of
// which fits a 4 MB per-XCD L2. Split the feature dim into 4 chunks of
// 64 B: each pass's working set = 50K x 64 B = 3.2 MB -> L2-RESIDENT.
// Passes write DISJOINT output chunks (no accumulation across passes), so
// no ordering is needed for correctness; block-index ordering
// (pass = blockIdx/gW) phases them in time for L2 residency.
// Addressing keeps 16 B/lane: 32-lane half-wave = one node; lane =
// (eg = hl>>2 in [0,8): edge sub-index, c = hl&3: 16-B part of the chunk).
// One row-gather inst fetches 8 edges' chunk parts -> 1 VMEM inst/edge
// TOTAL across 4 passes (same as R10), all L2-hot. 8 loads in flight.

__global__ __launch_bounds__(256) void k_agg1(const ushort_t* __restrict__ xb,
                                              const unsigned* __restrict__ packed,
                                              const unsigned* __restrict__ edata,
                                              ushort_t* __restrict__ ax,
                                              int Nn, int gW) {
    int bb = blockIdx.x;
    int p  = bb / gW;          // pass = feature chunk [p*32, p*32+32) bf16
    int nb = bb - p * gW;      // node-block within pass
    int v  = (nb * 256 + threadIdx.x) >> 5;
    int hl = threadIdx.x & 31;
    if (v >= Nn) return;
    int eg = hl >> 2;          // edge sub-index 0..7
    int c  = hl & 3;           // 16-B part: dims [c*8, c*8+8) of the chunk
    unsigned pk = packed[v];
    float dv = rsqrtf(1.0f + (float)(pk & 0x3FFFFFu) * (1.0f / 65536.0f));
    int n = min((int)(pk >> 22), MAXDEG);
    const unsigned* ed = edata + (size_t)v * MAXDEG;
    const ushort_t* base = xb + (size_t)p * 32 + (size_t)c * 8;

    float a[8] = {0.f, 0.f, 0.f, 0.f, 0.f, 0.f, 0.f, 0.f};
    if (eg == 0) {  // self-loop counted ONCE (xb' = dv*x_v; outer *dv -> dv^2)
        u16x8 pq = *(const u16x8*)(base + (size_t)v * 128);
#pragma unroll
        for (int k = 0; k < 8; ++k) a[k] = b2f((ushort_t)pq[k]);
    }
    // 32 edges per unrolled iteration (covers deg<=32 in one shot);
    // clamp-to-last + nw=0 keeps full depth on tails (dup loads L2-free).
    for (int i = 0; i < n; i += 32) {
        unsigned e2[4];
        u16x8 q[4];
        float nw[4];
#pragma unroll
        for (int u = 0; u < 4; ++u) {
            int idx = i + u * 8 + eg;
            e2[u] = ed[min(idx, n - 1)];
            int sN = (int)(e2[u] >> 15);
            q[u] = *(const u16x8*)(base + (size_t)sN * 128);
            nw[u] = (idx < n) ? (float)(e2[u] & 0x7FFFu) * (1.0f / 32768.0f) : 0.f;
        }
#pragma unroll
        for (int u = 0; u < 4; ++u)
#pragma unroll
            for (int k = 0; k < 8; ++k)
                a[k] += b2f((ushort_t)q[u][k]) * nw[u];
    }
    // reduce across the 8 edge-groups (c stays invariant under xor 4/8/16)
#pragma unroll
    for (int k = 0; k < 8; ++k) {
        a[k] += __shfl_xor(a[k], 4);
        a[k] += __shfl_xor(a[k], 8);
        a[k] += __shfl_xor(a[k], 16);
        a[k] *= dv;
    }
    if (eg == 0) {
        u16x8 o;
#pragma unroll
        for (int k = 0; k < 8; ++k) o[k] = f2b(a[k]);
        *(u16x8*)(ax + (size_t)v * 128 + (size_t)p * 32 + (size_t)c * 8) = o;
    }
}

// ---------------- parity-split half-wave gather core (agg2) ----------------
// ONE NODE PER 32-LANE HALF-WAVE, split by EDGE PARITY: lane = (pg = hl>>4,
// ld = hl&15). 16 lanes x ushort8 (16 B) cover the full 256 B row; group pg
// handles edges i+pg, i+pg+2, ... -> ONE row-gather instruction fetches TWO
// edges' rows. VMEM inst/edge = 1 (R10). Clamp-to-last + nw=0 tails.
// Rows are dinv[src]-prescaled: nw = wq/32768.

__device__ inline void agg_edges(const ushort_t* __restrict__ src,
                                 const unsigned* __restrict__ ed, int n,
                                 int ld, int pg, float* a) {
    for (int i = 0; i < n; i += 16) {
        unsigned e2[8];
#pragma unroll
        for (int j = 0; j < 8; ++j) e2[j] = ed[min(i + 2 * j + pg, n - 1)];
        u16x8 q[8];
        float nw[8];
#pragma unroll
        for (int j = 0; j < 8; ++j) {
            int sN = (int)(e2[j] >> 15);
            q[j] = ((const u16x8*)(src + (size_t)sN * 128))[ld];
            nw[j] = (i + 2 * j + pg < n)
                        ? (float)(e2[j] & 0x7FFFu) * (1.0f / 32768.0f)
                        : 0.f;
        }
#pragma unroll
        for (int j = 0; j < 8; ++j)
#pragma unroll
            for (int k = 0; k < 8; ++k)
                a[k] += b2f((ushort_t)q[j][k]) * nw[j];
    }
}

// ---------------- fused GEMM: h2 = dinv * (relu(ax @ W1^T + b1) @ W2^T) ----------------
// Block = 64 rows, 4 waves split the N dimension (no redundant W loads).
// Phase 1: wave w computes 64 rows x cols [w*64,w*64+64): W1 slice + a-frags
// fully prefetched into registers. ReLU'd 64x256 bf16 tile -> shared LDS.
// Phase 2: wave w computes 64 rows x cols [w*32,w*32+32) from LDS A-frags
// and prefetched W2 slice. Epilogue pre-scales rows by dinv[row] so k_agg2
// needs no per-edge dinv gather. MFMA 16x16x32 bf16 layouts: A row=lane&15,
// k=quad*8+j; B col=lane&15, k=quad*8+j; D col=lane&15, row=quad*4+reg.

__global__ __launch_bounds__(256, 2) void k_gemm_fused(const ushort_t* __restrict__ ax,
                                                       const ushort_t* __restrict__ W1b,
                                                       const float* __restrict__ b1v,
                                                       const ushort_t* __restrict__ W2b,
                                                       const float* __restrict__ dinv,
                                                       ushort_t* __restrict__ h2, int Nn) {
    __shared__ ushort_t tile[64][264];  // 33792 B; stride 264: 16B-aligned rows
    int tid = threadIdx.x, wid = tid >> 6, lane = tid & 63;
    int m = lane & 15, q = lane >> 4;
    int blk = blockIdx.x * 64;

    short8 wf[4][4];  // [nt][kt]
#pragma unroll
    for (int nt = 0; nt < 4; ++nt) {
        const ushort_t* wb = W1b + (size_t)(wid * 64 + nt * 16 + m) * 128 + q * 8;
#pragma unroll
        for (int kt = 0; kt < 4; ++kt) wf[nt][kt] = *(const short8*)(wb + kt * 32);
    }
    short8 af[4][4];  // [mi][kt]
#pragma unroll
    for (int mi = 0; mi < 4; ++mi) {
        int arow = blk + mi * 16 + m;
        bool rv = arow < Nn;
        const ushort_t* ab = ax + (size_t)arow * 128 + q * 8;
#pragma unroll
        for (int kt = 0; kt < 4; ++kt)
            af[mi][kt] = rv ? *(const short8*)(ab + kt * 32) : (short8)0;
    }

    float4v acc1[4][4];  // [mi][nt]
#pragma unroll
    for (int mi = 0; mi < 4; ++mi)
#pragma unroll
        for (int nt = 0; nt < 4; ++nt) acc1[mi][nt] = (float4v){0.f, 0.f, 0.f, 0.f};

#pragma unroll
    for (int kt = 0; kt < 4; ++kt)
#pragma unroll
        for (int mi = 0; mi < 4; ++mi)
#pragma unroll
            for (int nt = 0; nt < 4; ++nt)
                acc1[mi][nt] = __builtin_amdgcn_mfma_f32_16x16x32_bf16(
                    af[mi][kt], wf[nt][kt], acc1[mi][nt], 0, 0, 0);

#pragma unroll
    for (int nt = 0; nt < 4; ++nt) {
        int col = wid * 64 + nt * 16 + m;
        float bb = b1v[col];
#pragma unroll
        for (int mi = 0; mi < 4; ++mi) {
#pragma unroll
            for (int r = 0; r < 4; ++r) {
                float v = acc1[mi][nt][r] + bb;
                v = v > 0.f ? v : 0.f;
                tile[mi * 16 + q * 4 + r][col] = f2b(v);
            }
        }
    }
    __syncthreads();

    short8 w2f[2][8];  // [n2][kt]
#pragma unroll
    for (int n2 = 0; n2 < 2; ++n2) {
        const ushort_t* wb = W2b + (size_t)(wid * 32 + n2 * 16 + m) * 256 + q * 8;
#pragma unroll
        for (int kt = 0; kt < 8; ++kt) w2f[n2][kt] = *(const short8*)(wb + kt * 32);
    }

    float4v acc2[4][2];  // [mi][n2]
#pragma unroll
    for (int mi = 0; mi < 4; ++mi)
#pragma unroll
        for (int n2 = 0; n2 < 2; ++n2) acc2[mi][n2] = (float4v){0.f, 0.f, 0.f, 0.f};

#pragma unroll
    for (int kt = 0; kt < 8; ++kt) {
#pragma unroll
        for (int mi = 0; mi < 4; ++mi) {
            short8 a2 = *(const short8*)&tile[mi * 16 + m][kt * 32 + q * 8];
#pragma unroll
            for (int n2 = 0; n2 < 2; ++n2)
                acc2[mi][n2] = __builtin_amdgcn_mfma_f32_16x16x32_bf16(
                    a2, w2f[n2][kt], acc2[mi][n2], 0, 0, 0);
        }
    }

    float drow[4][4];  // dinv per output row (L2-hot)
#pragma unroll
    for (int mi = 0; mi < 4; ++mi)
#pragma unroll
        for (int r = 0; r < 4; ++r) {
            int row = blk + mi * 16 + q * 4 + r;
            drow[mi][r] = (row < Nn) ? dinv[row] : 0.f;
        }

#pragma unroll
    for (int mi = 0; mi < 4; ++mi) {
#pragma unroll
        for (int n2 = 0; n2 < 2; ++n2) {
            int col = wid * 32 + n2 * 16 + m;
#pragma unroll
            for (int r = 0; r < 4; ++r) {
                int row = blk + mi * 16 + q * 4 + r;
                if (row < Nn)
                    h2[(size_t)row * 128 + col] = f2b(acc2[mi][n2][r] * drow[mi][r]);
            }
        }
    }
}

// ---------------- aggregation 2 + bias + LayerNorm (fp32 out) ----------------
// h2 rows are dinv-prescaled: out_pre[v] = dv * (h2'[v] + sum_e w*h2'[s]) + b2.
// Parity-split half-wave per node; after the parity combine both groups hold
// identical a[8] -> 32-lane reduce counts each dim twice -> /256.

__global__ __launch_bounds__(256) void k_agg2_ln(const ushort_t* __restrict__ h2,
                                                 const unsigned* __restrict__ packed,
                                                 const unsigned* __restrict__ edata,
                                                 const float* __restrict__ b2v,
                                                 const float* __restrict__ gv,
                                                 const float* __restrict__ bev,
                                                 float* __restrict__ out, int Nn) {
    int v = (blockIdx.x * blockDim.x + threadIdx.x) >> 5;
    int hl = threadIdx.x & 31;
    if (v >= Nn) return;
    int pg = hl >> 4, ld = hl & 15;
    unsigned pk = packed[v];
    float dv = rsqrtf(1.0f + (float)(pk & 0x3FFFFFu) * (1.0f / 65536.0f));
    float a[8] = {0.f, 0.f, 0.f, 0.f, 0.f, 0.f, 0.f, 0.f};
    if (pg == 0) {
        u16x8 pq = ((const u16x8*)(h2 + (size_t)v * 128))[ld];
#pragma unroll
        for (int k = 0; k < 8; ++k) a[k] = b2f((ushort_t)pq[k]);
    }
    int n = min((int)(pk >> 22), MAXDEG);
    agg_edges(h2, edata + (size_t)v * MAXDEG, n, ld, pg, a);

    int d0 = ld * 8;
#pragma unroll
    for (int k = 0; k < 8; ++k) {
        a[k] += __shfl_xor(a[k], 16);
        a[k] = a[k] * dv + b2v[d0 + k];
    }

    // 32 lanes x 8 dims, each dim held twice (both parities) -> /256
    float ssum = 0.f, ssq = 0.f;
#pragma unroll
    for (int k = 0; k < 8; ++k) { ssum += a[k]; ssq += a[k] * a[k]; }
#pragma unroll
    for (int off = 1; off < 32; off <<= 1) {
        ssum += __shfl_xor(ssum, off);
        ssq += __shfl_xor(ssq, off);
    }
    float mu = ssum * (1.0f / 256.0f);
    float var = ssq * (1.0f / 256.0f) - mu * mu;
    float r = rsqrtf(var + 1e-5f);
    if (pg == 0) {
        float4v o1, o2;
#pragma unroll
        for (int k = 0; k < 4; ++k) {
            o1[k] = (a[k] - mu) * r * gv[d0 + k] + bev[d0 + k];
            o2[k] = (a[k + 4] - mu) * r * gv[d0 + 4 + k] + bev[d0 + 4 + k];
        }
        float4v* op = (float4v*)(out + (size_t)v * 128 + d0);
        op[0] = o1;
        op[1] = o2;
    }
}

// ---------------- launch ----------------

extern "C" void kernel_launch(void* const* d_in, const int* in_sizes, int n_in,
                              void* d_out, int out_size, void* d_ws, size_t ws_size,
                              hipStream_t stream) {
    const float* x   = (const float*)d_in[0];  // [N,128] f32
    const int*   ei  = (const int*)d_in[1];    // [2,E] int32/int64 (detected)
    const float* ew  = (const float*)d_in[2];  // [E] f32
    const float* W1  = (const float*)d_in[3];  // [256,128] f32
    const float* b1v = (const float*)d_in[4];  // [256]
    const float* W2  = (const float*)d_in[5];  // [128,256]
    const float* b2v = (const float*)d_in[6];  // [128]
    const float* gv  = (const float*)d_in[7];  // [128]
    const float* bev = (const float*)d_in[8];  // [128]
    float* out = (float*)d_out;

    const int Nn = in_sizes[0] / 128;
    const int E  = in_sizes[2];

    char* base = (char*)d_ws;
    size_t off = 0;
    auto alloc = [&](size_t bytes) {
        char* p = base + off;
        off = (off + bytes + 255) & ~(size_t)255;
        return p;
    };
    unsigned* packed = (unsigned*)alloc((size_t)Nn * 4);
    float*    dinv   = (float*)alloc((size_t)Nn * 4);
    unsigned* edata  = (unsigned*)alloc((size_t)Nn * MAXDEG * 4);
    ushort_t* xb     = (ushort_t*)alloc((size_t)Nn * 128 * 2);
    ushort_t* h2     = (ushort_t*)alloc((size_t)Nn * 128 * 2);
    ushort_t* W1b    = (ushort_t*)alloc(32768 * 2);
    ushort_t* W2b    = (ushort_t*)alloc(32768 * 2);
    // d_out (25.6 MB f32) staging: ax in the lower half (written by k_agg1,
    // read by gemm); xb_raw in the upper half (written by k_mega, read by
    // k_xscale, dead before k_agg1 runs). No overlap in space or time.
    ushort_t* ax     = (ushort_t*)d_out;
    ushort_t* xb_raw = (ushort_t*)d_out + (size_t)Nn * 128;
    (void)ws_size; (void)n_in; (void)out_size;

    int gE = (E + 255) / 256;
    int gX = (Nn * 32 + 255) / 256;   // float4 count / 256
    int gW = (Nn + 7) / 8;            // half-wave per node, 8 nodes per block
    int gG = (Nn + 63) / 64;          // 64 rows per block

    hipMemsetAsync(packed, 0, (size_t)Nn * 4, stream);
    k_mega<<<gE + gX + 256, 256, 0, stream>>>(ei, ew, x, W1, W2, packed, edata,
                                              xb_raw, W1b, W2b, E, Nn, gE, gX);
    k_xscale<<<gW, 256, 0, stream>>>(xb_raw, packed, dinv, xb, Nn);
    k_agg1<<<4 * gW, 256, 0, stream>>>(xb, packed, edata, ax, Nn, gW);
    k_gemm_fused<<<gG, 256, 0, stream>>>(ax, W1b, b1v, W2b, dinv, h2, Nn);
    k_agg2_ln<<<gW, 256, 0, stream>>>(h2, packed, edata, b2v, gv, bev, out, Nn);
}

// Round 14
// 225.433 us; speedup vs baseline: 1.0673x; 1.0673x over previous
//
#include <hip/hip_runtime.h>

typedef unsigned short ushort_t;
typedef __attribute__((ext_vector_type(8))) short short8;
typedef __attribute__((ext_vector_type(8))) unsigned short u16x8;
typedef __attribute__((ext_vector_type(4))) float float4v;

#define MAXDEG 48

__device__ inline float b2f(ushort_t u) {
    unsigned x = ((unsigned)u) << 16;
    return __builtin_bit_cast(float, x);
}
__device__ inline ushort_t f2b(float f) {
    unsigned x = __builtin_bit_cast(unsigned, f);
    unsigned r = (x + 0x7fffu + ((x >> 16) & 1u)) >> 16;
    return (ushort_t)r;
}

// Wave-uniform int64-vs-int32 edge_index detection: load the int2 pair at
// edge slot e (valid bytes in BOTH layouts); int64-little-endian => odd word
// is always 0. Any nonzero odd word in the wave => int32.
__device__ inline void load_edge(const int* __restrict__ ei, int e, int E,
                                 int& s, int& d) {
    int ec = min(e, E - 1);
    int2 c64 = ((const int2*)ei)[ec];
    unsigned long long m = __ballot(c64.y != 0);
    if (m != 0ull) {  // int32 layout
        s = ei[ec];
        d = ei[(size_t)E + ec];
    } else {          // int64 layout
        s = c64.x;
        d = ((const int2*)ei)[(size_t)E + ec].x;
    }
}

// ---------------- mega kernel: count + direct slot scatter + casts ----------------
// packed[d] (u32): bits[31:22] = edge count, bits[21:0] = sum(w) in 6.16
// fixed point. The atomic's returned count IS the slot rank:
// edata[d*MAXDEG + r] = (src<<15)|wq15 written immediately.
// Edge blocks (stalled on the far-atomic wall, ~2% VALU; scope-null R1,
// padding-null R4 => fabric per-op limit ~8 ops/cycle chip-wide) are
// INTERLEAVED 1:2 with x-cast blocks (BW-bound): cast traffic hides under
// the atomic wall (A/B'd: present -> 46-50 us; removed -> 51-53 us, R8).

__global__ __launch_bounds__(256) void k_mega(const int* __restrict__ ei,
                                              const float* __restrict__ w,
                                              const float* __restrict__ x,
                                              const float* __restrict__ W1,
                                              const float* __restrict__ W2,
                                              unsigned* packed,
                                              unsigned* __restrict__ edata,
                                              ushort_t* __restrict__ xb_raw,
                                              ushort_t* __restrict__ W1b,
                                              ushort_t* __restrict__ W2b,
                                              int E, int Nn, int gE, int gX) {
    int b = blockIdx.x;
    bool isEdge;
    int widx;
    if (3 * gE <= (int)gridDim.x) {  // interleaved layout: edge at b%3==0
        if (b < 3 * gE) {
            if (b % 3 == 0) { isEdge = true;  widx = b / 3; }
            else            { isEdge = false; widx = b - b / 3 - 1; }
        } else {
            isEdge = false; widx = b - gE;
        }
    } else {  // fallback: contiguous sections
        isEdge = b < gE;
        widx = isEdge ? b : b - gE;
    }

    if (isEdge) {
        int e = widx * 256 + threadIdx.x;
        int s, d;
        load_edge(ei, e, E, s, d);
        if (e < E) {
            if ((unsigned)s < (unsigned)Nn && (unsigned)d < (unsigned)Nn) {
                float wv = w[e];
                unsigned fx = (unsigned)(wv * 65536.0f + 0.5f);
                unsigned old = atomicAdd(packed + d, (1u << 22) | fx);
                int r = (int)(old >> 22);
                if (r < MAXDEG) {
                    unsigned wq = (unsigned)(wv * 32768.0f + 0.5f);
                    wq = min(wq, 32767u);
                    edata[(size_t)d * MAXDEG + r] = ((unsigned)s << 15) | wq;
                }
            }
        }
    } else if (widx < gX) {
        int i = widx * 256 + threadIdx.x;  // float4 index
        if (i < Nn * 32) {
            float4v v = ((const float4v*)x)[i];
            ushort4 o;
            o.x = f2b(v[0]); o.y = f2b(v[1]); o.z = f2b(v[2]); o.w = f2b(v[3]);
            ((ushort4*)xb_raw)[i] = o;
        }
    } else {
        int i = (widx - gX) * 256 + threadIdx.x;
        if (i < 32768) W1b[i] = f2b(W1[i]);
        else if (i < 65536) W2b[i - 32768] = f2b(W2[i - 32768]);
    }
}

// ---------------- xscale: xb = bf16(dinv[v] * xb_raw[v]) + dinv table ----------------
// Folding dinv[src] into the STORED rows removes the per-edge dinv gather
// from both agg kernels (R8: -22 us combined). Reads bf16 xb_raw (12.8 MB).

__global__ __launch_bounds__(256) void k_xscale(const ushort_t* __restrict__ xb_raw,
                                                const unsigned* __restrict__ packed,
                                                float* __restrict__ dinv,
                                                ushort_t* __restrict__ xb, int Nn) {
    int v = (blockIdx.x * blockDim.x + threadIdx.x) >> 5;
    int hl = threadIdx.x & 31;
    if (v >= Nn) return;
    unsigned pk = packed[v];
    float dv = rsqrtf(1.0f + (float)(pk & 0x3FFFFFu) * (1.0f / 65536.0f));
    if (hl == 0) dinv[v] = dv;
    ushort4 xr = ((const ushort4*)(xb_raw + (size_t)v * 128))[hl];
    ushort4 o;
    o.x = f2b(b2f(xr.x) * dv); o.y = f2b(b2f(xr.y) * dv);
    o.z = f2b(b2f(xr.z) * dv); o.w = f2b(b2f(xr.w) * dv);
    ((ushort4*)(xb + (size_t)v * 128))[hl] = o;
}

// ---------------- parity-split half-wave gather core ----------------
// ONE NODE PER 32-LANE HALF-WAVE, split by EDGE PARITY: lane = (pg = hl>>4,
// ld = hl&15). 16 lanes x ushort8 (16 B) cover the full 256 B row; group pg
// handles edges i+pg, i+pg+2, ... -> ONE row-gather instruction fetches TWO
// edges' rows (32 lanes x 16 B), and one edata instruction serves both
// parities' slot words. VMEM inst/edge = 1 (R10: -4 us vs 2/edge; the
// structural minimum -- R11 VALU-trim null, R13 L2-chunking negative:
// aggs are random-gather latency/queue-bound). Clamp-to-last + nw=0 keeps
// tails full-depth. Rows are dinv[src]-prescaled: nw = wq/32768.

__device__ inline void agg_edges(const ushort_t* __restrict__ src,
                                 const unsigned* __restrict__ ed, int n,
                                 int ld, int pg, float* a) {
    for (int i = 0; i < n; i += 16) {
        unsigned e2[8];
#pragma unroll
        for (int j = 0; j < 8; ++j) e2[j] = ed[min(i + 2 * j + pg, n - 1)];
        u16x8 q[8];
        float nw[8];
#pragma unroll
        for (int j = 0; j < 8; ++j) {
            int sN = (int)(e2[j] >> 15);
            q[j] = ((const u16x8*)(src + (size_t)sN * 128))[ld];
            nw[j] = (i + 2 * j + pg < n)
                        ? (float)(e2[j] & 0x7FFFu) * (1.0f / 32768.0f)
                        : 0.f;
        }
#pragma unroll
        for (int j = 0; j < 8; ++j)
#pragma unroll
            for (int k = 0; k < 8; ++k)
                a[k] += b2f((ushort_t)q[j][k]) * nw[j];
    }
}

// aggregation 1: ax = A_norm @ x  (bf16 in/out, fp32 acc)
// xb rows are dinv-prescaled: ax[v] = dv * (xb'[v] + sum_e w * xb'[s]).

__global__ __launch_bounds__(256) void k_agg1(const ushort_t* __restrict__ xb,
                                              const unsigned* __restrict__ packed,
                                              const unsigned* __restrict__ edata,
                                              ushort_t* __restrict__ ax, int Nn) {
    int v = (blockIdx.x * blockDim.x + threadIdx.x) >> 5;
    int hl = threadIdx.x & 31;
    if (v >= Nn) return;
    int pg = hl >> 4, ld = hl & 15;
    unsigned pk = packed[v];
    float dv = rsqrtf(1.0f + (float)(pk & 0x3FFFFFu) * (1.0f / 65536.0f));
    float a[8] = {0.f, 0.f, 0.f, 0.f, 0.f, 0.f, 0.f, 0.f};
    if (pg == 0) {  // self-loop (xb' = dv*x_v; outer *dv gives dv^2)
        u16x8 pq = ((const u16x8*)(xb + (size_t)v * 128))[ld];
#pragma unroll
        for (int k = 0; k < 8; ++k) a[k] = b2f((ushort_t)pq[k]);
    }
    int n = min((int)(pk >> 22), MAXDEG);
    agg_edges(xb, edata + (size_t)v * MAXDEG, n, ld, pg, a);
#pragma unroll
    for (int k = 0; k < 8; ++k) {
        a[k] += __shfl_xor(a[k], 16);
        a[k] *= dv;
    }
    if (pg == 0) {
        u16x8 o;
#pragma unroll
        for (int k = 0; k < 8; ++k) o[k] = f2b(a[k]);
        ((u16x8*)(ax + (size_t)v * 128))[ld] = o;
    }
}

// ---------------- fused GEMM: h2 = dinv * (relu(ax @ W1^T + b1) @ W2^T) ----------------
// Block = 64 rows, 4 waves split the N dimension (no redundant W loads).
// Phase 1: wave w computes 64 rows x cols [w*64,w*64+64): W1 slice + a-frags
// fully prefetched into registers. ReLU'd 64x256 bf16 tile -> shared LDS.
// Phase 2: wave w computes 64 rows x cols [w*32,w*32+32) from LDS A-frags
// and prefetched W2 slice. Epilogue pre-scales rows by dinv[row] so k_agg2
// needs no per-edge dinv gather. MFMA 16x16x32 bf16 layouts: A row=lane&15,
// k=quad*8+j; B col=lane&15, k=quad*8+j; D col=lane&15, row=quad*4+reg.

__global__ __launch_bounds__(256, 2) void k_gemm_fused(const ushort_t* __restrict__ ax,
                                                       const ushort_t* __restrict__ W1b,
                                                       const float* __restrict__ b1v,
                                                       const ushort_t* __restrict__ W2b,
                                                       const float* __restrict__ dinv,
                                                       ushort_t* __restrict__ h2, int Nn) {
    __shared__ ushort_t tile[64][264];  // 33792 B; stride 264: 16B-aligned rows
    int tid = threadIdx.x, wid = tid >> 6, lane = tid & 63;
    int m = lane & 15, q = lane >> 4;
    int blk = blockIdx.x * 64;

    short8 wf[4][4];  // [nt][kt]
#pragma unroll
    for (int nt = 0; nt < 4; ++nt) {
        const ushort_t* wb = W1b + (size_t)(wid * 64 + nt * 16 + m) * 128 + q * 8;
#pragma unroll
        for (int kt = 0; kt < 4; ++kt) wf[nt][kt] = *(const short8*)(wb + kt * 32);
    }
    short8 af[4][4];  // [mi][kt]
#pragma unroll
    for (int mi = 0; mi < 4; ++mi) {
        int arow = blk + mi * 16 + m;
        bool rv = arow < Nn;
        const ushort_t* ab = ax + (size_t)arow * 128 + q * 8;
#pragma unroll
        for (int kt = 0; kt < 4; ++kt)
            af[mi][kt] = rv ? *(const short8*)(ab + kt * 32) : (short8)0;
    }

    float4v acc1[4][4];  // [mi][nt]
#pragma unroll
    for (int mi = 0; mi < 4; ++mi)
#pragma unroll
        for (int nt = 0; nt < 4; ++nt) acc1[mi][nt] = (float4v){0.f, 0.f, 0.f, 0.f};

#pragma unroll
    for (int kt = 0; kt < 4; ++kt)
#pragma unroll
        for (int mi = 0; mi < 4; ++mi)
#pragma unroll
            for (int nt = 0; nt < 4; ++nt)
                acc1[mi][nt] = __builtin_amdgcn_mfma_f32_16x16x32_bf16(
                    af[mi][kt], wf[nt][kt], acc1[mi][nt], 0, 0, 0);

#pragma unroll
    for (int nt = 0; nt < 4; ++nt) {
        int col = wid * 64 + nt * 16 + m;
        float bb = b1v[col];
#pragma unroll
        for (int mi = 0; mi < 4; ++mi) {
#pragma unroll
            for (int r = 0; r < 4; ++r) {
                float v = acc1[mi][nt][r] + bb;
                v = v > 0.f ? v : 0.f;
                tile[mi * 16 + q * 4 + r][col] = f2b(v);
            }
        }
    }
    __syncthreads();

    short8 w2f[2][8];  // [n2][kt]
#pragma unroll
    for (int n2 = 0; n2 < 2; ++n2) {
        const ushort_t* wb = W2b + (size_t)(wid * 32 + n2 * 16 + m) * 256 + q * 8;
#pragma unroll
        for (int kt = 0; kt < 8; ++kt) w2f[n2][kt] = *(const short8*)(wb + kt * 32);
    }

    float4v acc2[4][2];  // [mi][n2]
#pragma unroll
    for (int mi = 0; mi < 4; ++mi)
#pragma unroll
        for (int n2 = 0; n2 < 2; ++n2) acc2[mi][n2] = (float4v){0.f, 0.f, 0.f, 0.f};

#pragma unroll
    for (int kt = 0; kt < 8; ++kt) {
#pragma unroll
        for (int mi = 0; mi < 4; ++mi) {
            short8 a2 = *(const short8*)&tile[mi * 16 + m][kt * 32 + q * 8];
#pragma unroll
            for (int n2 = 0; n2 < 2; ++n2)
                acc2[mi][n2] = __builtin_amdgcn_mfma_f32_16x16x32_bf16(
                    a2, w2f[n2][kt], acc2[mi][n2], 0, 0, 0);
        }
    }

    float drow[4][4];  // dinv per output row (L2-hot)
#pragma unroll
    for (int mi = 0; mi < 4; ++mi)
#pragma unroll
        for (int r = 0; r < 4; ++r) {
            int row = blk + mi * 16 + q * 4 + r;
            drow[mi][r] = (row < Nn) ? dinv[row] : 0.f;
        }

#pragma unroll
    for (int mi = 0; mi < 4; ++mi) {
#pragma unroll
        for (int n2 = 0; n2 < 2; ++n2) {
            int col = wid * 32 + n2 * 16 + m;
#pragma unroll
            for (int r = 0; r < 4; ++r) {
                int row = blk + mi * 16 + q * 4 + r;
                if (row < Nn)
                    h2[(size_t)row * 128 + col] = f2b(acc2[mi][n2][r] * drow[mi][r]);
            }
        }
    }
}

// ---------------- aggregation 2 + bias + LayerNorm (fp32 out) ----------------
// h2 rows are dinv-prescaled: out_pre[v] = dv * (h2'[v] + sum_e w*h2'[s]) + b2.
// Parity-split half-wave per node; after the parity combine both groups hold
// identical a[8] -> 32-lane reduce counts each dim twice -> /256.

__global__ __launch_bounds__(256) void k_agg2_ln(const ushort_t* __restrict__ h2,
                                                 const unsigned* __restrict__ packed,
                                                 const unsigned* __restrict__ edata,
                                                 const float* __restrict__ b2v,
                                                 const float* __restrict__ gv,
                                                 const float* __restrict__ bev,
                                                 float* __restrict__ out, int Nn) {
    int v = (blockIdx.x * blockDim.x + threadIdx.x) >> 5;
    int hl = threadIdx.x & 31;
    if (v >= Nn) return;
    int pg = hl >> 4, ld = hl & 15;
    unsigned pk = packed[v];
    float dv = rsqrtf(1.0f + (float)(pk & 0x3FFFFFu) * (1.0f / 65536.0f));
    float a[8] = {0.f, 0.f, 0.f, 0.f, 0.f, 0.f, 0.f, 0.f};
    if (pg == 0) {
        u16x8 pq = ((const u16x8*)(h2 + (size_t)v * 128))[ld];
#pragma unroll
        for (int k = 0; k < 8; ++k) a[k] = b2f((ushort_t)pq[k]);
    }
    int n = min((int)(pk >> 22), MAXDEG);
    agg_edges(h2, edata + (size_t)v * MAXDEG, n, ld, pg, a);

    int d0 = ld * 8;
#pragma unroll
    for (int k = 0; k < 8; ++k) {
        a[k] += __shfl_xor(a[k], 16);
        a[k] = a[k] * dv + b2v[d0 + k];
    }

    // 32 lanes x 8 dims, each dim held twice (both parities) -> /256
    float ssum = 0.f, ssq = 0.f;
#pragma unroll
    for (int k = 0; k < 8; ++k) { ssum += a[k]; ssq += a[k] * a[k]; }
#pragma unroll
    for (int off = 1; off < 32; off <<= 1) {
        ssum += __shfl_xor(ssum, off);
        ssq += __shfl_xor(ssq, off);
    }
    float mu = ssum * (1.0f / 256.0f);
    float var = ssq * (1.0f / 256.0f) - mu * mu;
    float r = rsqrtf(var + 1e-5f);
    if (pg == 0) {
        float4v o1, o2;
#pragma unroll
        for (int k = 0; k < 4; ++k) {
            o1[k] = (a[k] - mu) * r * gv[d0 + k] + bev[d0 + k];
            o2[k] = (a[k + 4] - mu) * r * gv[d0 + 4 + k] + bev[d0 + 4 + k];
        }
        float4v* op = (float4v*)(out + (size_t)v * 128 + d0);
        op[0] = o1;
        op[1] = o2;
    }
}

// ---------------- launch ----------------

extern "C" void kernel_launch(void* const* d_in, const int* in_sizes, int n_in,
                              void* d_out, int out_size, void* d_ws, size_t ws_size,
                              hipStream_t stream) {
    const float* x   = (const float*)d_in[0];  // [N,128] f32
    const int*   ei  = (const int*)d_in[1];    // [2,E] int32/int64 (detected)
    const float* ew  = (const float*)d_in[2];  // [E] f32
    const float* W1  = (const float*)d_in[3];  // [256,128] f32
    const float* b1v = (const float*)d_in[4];  // [256]
    const float* W2  = (const float*)d_in[5];  // [128,256]
    const float* b2v = (const float*)d_in[6];  // [128]
    const float* gv  = (const float*)d_in[7];  // [128]
    const float* bev = (const float*)d_in[8];  // [128]
    float* out = (float*)d_out;

    const int Nn = in_sizes[0] / 128;
    const int E  = in_sizes[2];

    char* base = (char*)d_ws;
    size_t off = 0;
    auto alloc = [&](size_t bytes) {
        char* p = base + off;
        off = (off + bytes + 255) & ~(size_t)255;
        return p;
    };
    unsigned* packed = (unsigned*)alloc((size_t)Nn * 4);
    float*    dinv   = (float*)alloc((size_t)Nn * 4);
    unsigned* edata  = (unsigned*)alloc((size_t)Nn * MAXDEG * 4);
    ushort_t* xb     = (ushort_t*)alloc((size_t)Nn * 128 * 2);
    ushort_t* h2     = (ushort_t*)alloc((size_t)Nn * 128 * 2);
    ushort_t* W1b    = (ushort_t*)alloc(32768 * 2);
    ushort_t* W2b    = (ushort_t*)alloc(32768 * 2);
    // d_out (25.6 MB f32) staging: ax in the lower half (written by k_agg1,
    // read by gemm); xb_raw in the upper half (written by k_mega, read by
    // k_xscale, dead before k_agg1 runs). No overlap in space or time.
    ushort_t* ax     = (ushort_t*)d_out;
    ushort_t* xb_raw = (ushort_t*)d_out + (size_t)Nn * 128;
    (void)ws_size; (void)n_in; (void)out_size;

    int gE = (E + 255) / 256;
    int gX = (Nn * 32 + 255) / 256;   // float4 count / 256
    int gW = (Nn + 7) / 8;            // half-wave per node, 8 nodes per block
    int gG = (Nn + 63) / 64;          // 64 rows per block

    hipMemsetAsync(packed, 0, (size_t)Nn * 4, stream);
    k_mega<<<gE + gX + 256, 256, 0, stream>>>(ei, ew, x, W1, W2, packed, edata,
                                              xb_raw, W1b, W2b, E, Nn, gE, gX);
    k_xscale<<<gW, 256, 0, stream>>>(xb_raw, packed, dinv, xb, Nn);
    k_agg1<<<gW, 256, 0, stream>>>(xb, packed, edata, ax, Nn);
    k_gemm_fused<<<gG, 256, 0, stream>>>(ax, W1b, b1v, W2b, dinv, h2, Nn);
    k_agg2_ln<<<gW, 256, 0, stream>>>(h2, packed, edata, b2v, gv, bev, out, Nn);
}